// Round 3
// baseline (555.606 us; speedup 1.0000x reference)
//
#include <hip/hip_runtime.h>

#define N_NODES 100000
#define F_IN 128
#define HID 256
#define NCLS 64
#define N_EDGES 1600000

typedef _Float16 f16;
typedef f16 half8 __attribute__((ext_vector_type(8)));
typedef f16 half4 __attribute__((ext_vector_type(4)));
typedef float f32x4 __attribute__((ext_vector_type(4)));
typedef unsigned long long u64;

#define FIXED_SCALE 67108864.0f   // 2^26

// ---------------------------------------------------------------------------
// degp[i]: packed u64 = (edge_count << 40) | fixed_point_26(weighted_deg)
// Init = fixed-point 1.0 (the self-loop weight), count 0.
// ---------------------------------------------------------------------------
__global__ void k_init(unsigned long long* __restrict__ degp, int n) {
    int i = blockIdx.x * 256 + threadIdx.x;
    if (i < n) degp[i] = (unsigned long long)(1u << 26);
}

// Mega kernel: k_deg atomics (blocks [0,EB)) run with idle VALU/HBM pipes;
// fp16 conversions ride along in trailing blocks, hidden under the atomic
// latency envelope. All parts are mutually independent.
#define EB   6250    // N_EDGES/256
#define XB   12500   // N_NODES*F_IN/4/256
#define W0B  128     // F_IN*HID/256
#define W1B  256     // HID*HID/256
#define W2B  64      // HID*NCLS/256
__global__ __launch_bounds__(256) void mega1(
        const int* __restrict__ dst, const float* __restrict__ ew,
        unsigned long long* __restrict__ degp, int* __restrict__ seq,
        const float* __restrict__ x, f16* __restrict__ xh,
        const float* __restrict__ W0, f16* __restrict__ Wt0,
        const float* __restrict__ W1, f16* __restrict__ Wt1,
        const float* __restrict__ W2, f16* __restrict__ Wt2) {
    int bid = blockIdx.x;
    int t = threadIdx.x;
    if (bid < EB) {
        int i = bid * 256 + t;
        if (i < N_EDGES) {
            unsigned long long c = (1ULL << 40) |
                (unsigned long long)__float2uint_rn(ew[i] * FIXED_SCALE);
            unsigned long long old = atomicAdd(&degp[dst[i]], c);
            seq[i] = (int)(old >> 40);       // this edge's slot within its dst segment
        }
    } else if (bid < EB + XB) {
        int i = (bid - EB) * 256 + t;        // float4 index over x
        if (i < N_NODES * (F_IN / 4)) {
            float4 v = *(const float4*)&x[(size_t)i * 4];
            half4 o;
            o[0] = (f16)v.x; o[1] = (f16)v.y; o[2] = (f16)v.z; o[3] = (f16)v.w;
            *(half4*)&xh[(size_t)i * 4] = o;
        }
    } else if (bid < EB + XB + W0B) {
        int i = (bid - EB - XB) * 256 + t;   // W0[F_IN][HID] -> Wt0[HID][F_IN]
        int k = i / HID, d = i % HID;
        Wt0[d * F_IN + k] = (f16)W0[i];
    } else if (bid < EB + XB + W0B + W1B) {
        int i = (bid - EB - XB - W0B) * 256 + t;
        int k = i / HID, d = i % HID;
        Wt1[d * HID + k] = (f16)W1[i];
    } else {
        int i = (bid - EB - XB - W0B - W1B) * 256 + t;
        int k = i / NCLS, d = i % NCLS;
        Wt2[d * HID + k] = (f16)W2[i];
    }
}

// k_dis folded into scan1: compute cnt/dis/selfnorm from degp inline, then scan.
__global__ void k_scan1(const unsigned long long* __restrict__ degp,
                        int* __restrict__ cnt, float* __restrict__ dis,
                        float* __restrict__ selfnorm,
                        int* __restrict__ incl, int* __restrict__ bsum, int n) {
    __shared__ int s[256];
    int t = threadIdx.x;
    int i = blockIdx.x * 256 + t;
    int v = 0;
    if (i < n) {
        unsigned long long p = degp[i];
        v = (int)(p >> 40);
        cnt[i] = v;
        float deg = (float)(p & ((1ULL << 40) - 1)) * (1.0f / FIXED_SCALE);
        float d = rsqrtf(deg);
        dis[i] = d;
        selfnorm[i] = d * d;
    }
    s[t] = v;
    __syncthreads();
    #pragma unroll
    for (int off = 1; off < 256; off <<= 1) {
        int x = (t >= off) ? s[t - off] : 0;
        __syncthreads();
        s[t] += x;
        __syncthreads();
    }
    if (i < n) incl[i] = s[t];
    if (t == 255) bsum[blockIdx.x] = s[255];
}

__global__ void k_scan2(const int* __restrict__ bsum, int* __restrict__ boff, int nb) {
    __shared__ int s[512];
    int t = threadIdx.x;
    int v = (t < nb) ? bsum[t] : 0;
    s[t] = v;
    __syncthreads();
    #pragma unroll
    for (int off = 1; off < 512; off <<= 1) {
        int x = (t >= off) ? s[t - off] : 0;
        __syncthreads();
        s[t] += x;
        __syncthreads();
    }
    if (t < nb) boff[t] = s[t] - v;
}

// row[i] = global exclusive start (in-place over incl); row is NOT mutated later
__global__ void k_scan3(int* __restrict__ row, const int* __restrict__ cnt,
                        const int* __restrict__ boff, int n) {
    int i = blockIdx.x * 256 + threadIdx.x;
    if (i < n) row[i] = row[i] - cnt[i] + boff[i >> 8];
}

// atomic-free placement: pos = row_start[dst] + seq (from mega1's atomic return)
__global__ void k_place(const int* __restrict__ src, const int* __restrict__ dst,
                        const float* __restrict__ w, const int* __restrict__ seq,
                        const int* __restrict__ row, const float* __restrict__ dis,
                        int2* __restrict__ csr, int e) {
    int i = blockIdx.x * 256 + threadIdx.x;
    if (i < e) {
        int s = src[i], d = dst[i];
        float nw = dis[s] * w[i] * dis[d];
        int pos = row[d] + seq[i];
        csr[pos] = make_int2(s, __float_as_int(nw));
    }
}

// ---------------------------------------------------------------------------
// MFMA GEMM: out[n, c] = sum_k in[n, k] * W[k, c]  (+bias, relu if BIAS_RELU)
// Block tile 128x64, 4 waves, each wave 32 rows x 64 cols = 2x4 mfma 16x16x32.
// Round-0-verified VGPR-staging body; 1D grid + bijective XCD-chunk swizzle so
// the NB column-blocks sharing an A-panel land on the same XCD's L2.
// ---------------------------------------------------------------------------
template <int K, int DOUT, bool BIAS_RELU>
__global__ __launch_bounds__(256) void gemm_mfma(const f16* __restrict__ in,
                                                 const f16* __restrict__ Wt,  // [DOUT][K]
                                                 const float* __restrict__ bias,
                                                 f16* __restrict__ out,
                                                 int nNodes) {
    constexpr int BM = 128, BN = 64, BK = 32;
    constexpr int NB = DOUT / BN;
    constexpr int AP = 40;
    constexpr int CP = 72;
    constexpr int SMEM = (BM * AP + BN * AP) > (BM * CP) ? (BM * AP + BN * AP) : (BM * CP);
    __shared__ f16 smem[SMEM];
    f16* As = smem;
    f16* Bs = smem + BM * AP;

    // bijective XCD-chunked swizzle (m204): dispatched block b (XCD ~ b%8)
    // processes work index wk so each XCD gets a contiguous chunk.
    const int nwg = gridDim.x;
    const int b = blockIdx.x;
    const int q = nwg >> 3, r = nwg & 7, xcd = b & 7;
    const int wk = (xcd < r ? xcd * (q + 1) : r * (q + 1) + (xcd - r) * q) + (b >> 3);
    const int bx = wk / NB, by = wk % NB;

    const int t = threadIdx.x;
    const int w = t >> 6;
    const int lane = t & 63;
    const int quad = lane >> 4;
    const int l16 = lane & 15;
    const int nodeBase = bx * BM;
    const int colBase = by * BN;

    f32x4 acc[2][4] = {};

    for (int k0 = 0; k0 < K; k0 += BK) {
        {
            int koff = (t & 3) * 8;
            #pragma unroll
            for (int p = 0; p < 2; ++p) {
                int r2 = (t >> 2) + p * 64;
                int gn = nodeBase + r2;
                if (gn >= nNodes) gn = nNodes - 1;
                half8 v = *(const half8*)&in[(size_t)gn * K + k0 + koff];
                *(half8*)&As[r2 * AP + koff] = v;
            }
        }
        {
            int koff = (t & 3) * 8;
            int c = t >> 2;
            half8 v = *(const half8*)&Wt[(size_t)(colBase + c) * K + k0 + koff];
            *(half8*)&Bs[c * AP + koff] = v;
        }
        __syncthreads();

        half8 a[2];
        #pragma unroll
        for (int rt = 0; rt < 2; ++rt)
            a[rt] = *(const half8*)&As[(w * 32 + rt * 16 + l16) * AP + quad * 8];
        #pragma unroll
        for (int ct = 0; ct < 4; ++ct) {
            half8 bf = *(const half8*)&Bs[(ct * 16 + l16) * AP + quad * 8];
            acc[0][ct] = __builtin_amdgcn_mfma_f32_16x16x32_f16(a[0], bf, acc[0][ct], 0, 0, 0);
            acc[1][ct] = __builtin_amdgcn_mfma_f32_16x16x32_f16(a[1], bf, acc[1][ct], 0, 0, 0);
        }
        __syncthreads();
    }

    float bv[4];
    #pragma unroll
    for (int ct = 0; ct < 4; ++ct)
        bv[ct] = BIAS_RELU ? bias[colBase + ct * 16 + l16] : 0.0f;

    f16* Cs = smem;
    #pragma unroll
    for (int rt = 0; rt < 2; ++rt)
        #pragma unroll
        for (int ct = 0; ct < 4; ++ct)
            #pragma unroll
            for (int rr2 = 0; rr2 < 4; ++rr2) {
                int rr = w * 32 + rt * 16 + quad * 4 + rr2;
                int cc = ct * 16 + l16;
                float v = acc[rt][ct][rr2];
                if (BIAS_RELU) v = fmaxf(v + bv[ct], 0.0f);
                Cs[rr * CP + cc] = (f16)v;
            }
    __syncthreads();
    #pragma unroll
    for (int p = 0; p < 4; ++p) {
        int rr = (t >> 3) + p * 32;
        int gn = nodeBase + rr;
        int chunk = (t & 7) * 8;
        if (gn < nNodes)
            *(half8*)&out[(size_t)gn * DOUT + colBase + chunk] =
                *(const half8*)&Cs[rr * CP + chunk];
    }
}

// ---------------------------------------------------------------------------
// CSR aggregation (fp16 h): out[d,:] = sn[d]*h[d,:] (+bias) + sum_e w_e*h[src_e,:]
// TPN lanes per node, 8 cols per lane (half8 = 16B), fp32 accumulate.
// Unroll-4: all 4 csr loads (nt, u64) hoisted before the 4 indirect h loads
// -> 2x in-flight bytes per thread vs unroll-2 (MLP lever).
// Outputs stored nontemporal: the 25-50 MB write stream must not evict h
// from the 4 MB per-XCD L2s.
// ---------------------------------------------------------------------------
template <int DOUT, int TPN, bool HAS_BIAS, bool OUT_F32>
__global__ __launch_bounds__(256) void agg_csr(const f16* __restrict__ h,
                                               const int2* __restrict__ csr,
                                               const int* __restrict__ row,
                                               const int* __restrict__ cnt,
                                               const float* __restrict__ sn,
                                               const float* __restrict__ bias,
                                               void* __restrict__ outv, int nNodes) {
    constexpr int NPB = 256 / TPN;
    int node = blockIdx.x * NPB + threadIdx.x / TPN;
    if (node >= nNodes) return;
    int lane = threadIdx.x % TPN;
    int col = lane * 8;

    float s = sn[node];
    half8 hv = *(const half8*)&h[(size_t)node * DOUT + col];
    float acc[8];
    #pragma unroll
    for (int i = 0; i < 8; ++i)
        acc[i] = s * (float)hv[i] + (HAS_BIAS ? bias[col + i] : 0.0f);

    int e = row[node];
    int end = e + cnt[node];
    const u64* csr64 = (const u64*)csr;

    for (; e + 3 < end; e += 4) {
        u64 p0 = __builtin_nontemporal_load(csr64 + e);
        u64 p1 = __builtin_nontemporal_load(csr64 + e + 1);
        u64 p2 = __builtin_nontemporal_load(csr64 + e + 2);
        u64 p3 = __builtin_nontemporal_load(csr64 + e + 3);
        const half8 a0 = *(const half8*)&h[(size_t)(unsigned)(p0 & 0xffffffffu) * DOUT + col];
        const half8 a1 = *(const half8*)&h[(size_t)(unsigned)(p1 & 0xffffffffu) * DOUT + col];
        const half8 a2 = *(const half8*)&h[(size_t)(unsigned)(p2 & 0xffffffffu) * DOUT + col];
        const half8 a3 = *(const half8*)&h[(size_t)(unsigned)(p3 & 0xffffffffu) * DOUT + col];
        float w0 = __int_as_float((int)(p0 >> 32));
        float w1 = __int_as_float((int)(p1 >> 32));
        float w2 = __int_as_float((int)(p2 >> 32));
        float w3 = __int_as_float((int)(p3 >> 32));
        #pragma unroll
        for (int i = 0; i < 8; ++i)
            acc[i] += w0 * (float)a0[i] + w1 * (float)a1[i]
                    + w2 * (float)a2[i] + w3 * (float)a3[i];
    }
    for (; e + 1 < end; e += 2) {
        u64 p0 = __builtin_nontemporal_load(csr64 + e);
        u64 p1 = __builtin_nontemporal_load(csr64 + e + 1);
        const half8 a0 = *(const half8*)&h[(size_t)(unsigned)(p0 & 0xffffffffu) * DOUT + col];
        const half8 a1 = *(const half8*)&h[(size_t)(unsigned)(p1 & 0xffffffffu) * DOUT + col];
        float w0 = __int_as_float((int)(p0 >> 32));
        float w1 = __int_as_float((int)(p1 >> 32));
        #pragma unroll
        for (int i = 0; i < 8; ++i)
            acc[i] += w0 * (float)a0[i] + w1 * (float)a1[i];
    }
    if (e < end) {
        u64 p0 = __builtin_nontemporal_load(csr64 + e);
        const half8 a0 = *(const half8*)&h[(size_t)(unsigned)(p0 & 0xffffffffu) * DOUT + col];
        float w0 = __int_as_float((int)(p0 >> 32));
        #pragma unroll
        for (int i = 0; i < 8; ++i) acc[i] += w0 * (float)a0[i];
    }

    if (OUT_F32) {
        float* out = (float*)outv;
        f32x4 r0, r1;
        r0[0] = acc[0]; r0[1] = acc[1]; r0[2] = acc[2]; r0[3] = acc[3];
        r1[0] = acc[4]; r1[1] = acc[5]; r1[2] = acc[6]; r1[3] = acc[7];
        __builtin_nontemporal_store(r0, (f32x4*)&out[(size_t)node * DOUT + col]);
        __builtin_nontemporal_store(r1, (f32x4*)&out[(size_t)node * DOUT + col + 4]);
    } else {
        f16* out = (f16*)outv;
        half8 o;
        #pragma unroll
        for (int i = 0; i < 8; ++i) o[i] = (f16)acc[i];
        __builtin_nontemporal_store(*(const f32x4*)&o,
                                    (f32x4*)&out[(size_t)node * DOUT + col]);
    }
}

// ---------------------------------------------------------------------------
extern "C" void kernel_launch(void* const* d_in, const int* in_sizes, int n_in,
                              void* d_out, int out_size, void* d_ws, size_t ws_size,
                              hipStream_t stream) {
    const float* x  = (const float*)d_in[0];
    const int*   ei = (const int*)d_in[1];
    const float* ew = (const float*)d_in[2];
    const float* W0 = (const float*)d_in[3];
    const float* b0 = (const float*)d_in[4];
    const float* W1 = (const float*)d_in[5];
    const float* b1 = (const float*)d_in[6];
    const float* W2 = (const float*)d_in[7];
    const float* b2 = (const float*)d_in[8];
    const int* src = ei;
    const int* dst = ei + N_EDGES;
    float* outp = (float*)d_out;

    // workspace carve-up (8B-aligned first)
    char* ws = (char*)d_ws;
    unsigned long long* degp = (unsigned long long*)ws;  ws += N_NODES * 8;
    int2*  csr      = (int2*)ws;   ws += (size_t)N_EDGES * 8;
    int*   seq      = (int*)ws;    ws += (size_t)N_EDGES * 4;
    float* dis      = (float*)ws;  ws += N_NODES * 4;
    float* selfnorm = (float*)ws;  ws += N_NODES * 4;
    int*   cnt      = (int*)ws;    ws += N_NODES * 4;
    int*   row      = (int*)ws;    ws += N_NODES * 4;
    int*   bsum     = (int*)ws;    ws += 512 * 4;
    int*   boff     = (int*)ws;    ws += 512 * 4;
    f16*   xh       = (f16*)ws;    ws += (size_t)N_NODES * F_IN * 2;
    f16*   Wt0      = (f16*)ws;    ws += F_IN * HID * 2;
    f16*   Wt1      = (f16*)ws;    ws += HID * HID * 2;
    f16*   Wt2      = (f16*)ws;    ws += HID * NCLS * 2;
    f16*   bufA     = (f16*)ws;    ws += (size_t)N_NODES * HID * 2;
    f16*   bufB     = (f16*)ws;    ws += (size_t)N_NODES * HID * 2;

    const int nb = (N_NODES + 255) / 256;   // 391
    const int eb = (N_EDGES + 255) / 256;   // 6250

    // ---- CSR build + norm (conversions hidden under the atomic pass) ----
    k_init<<<nb, 256, 0, stream>>>(degp, N_NODES);
    mega1<<<EB + XB + W0B + W1B + W2B, 256, 0, stream>>>(
        dst, ew, degp, seq, x, xh, W0, Wt0, W1, Wt1, W2, Wt2);
    k_scan1<<<nb, 256, 0, stream>>>(degp, cnt, dis, selfnorm, row, bsum, N_NODES);
    k_scan2<<<1, 512, 0, stream>>>(bsum, boff, nb);
    k_scan3<<<nb, 256, 0, stream>>>(row, cnt, boff, N_NODES);
    k_place<<<eb, 256, 0, stream>>>(src, dst, ew, seq, row, dis, csr, N_EDGES);

    const int gX = (N_NODES + 127) / 128;   // 782

    // ---- layer 1: g1 = A*X (128-wide gather), H1 = relu(g1 @ W0 + b0) ----
    agg_csr<F_IN, 16, false, false><<<(N_NODES + 15) / 16, 256, 0, stream>>>(
        xh, csr, row, cnt, selfnorm, nullptr, bufA, N_NODES);
    gemm_mfma<F_IN, HID, true><<<gX * (HID / 64), 256, 0, stream>>>(bufA, Wt0, b0, bufB, N_NODES);

    // ---- layer 2: g2 = A*H1 (256-wide gather), H2 = relu(g2 @ W1 + b1) ----
    agg_csr<HID, 32, false, false><<<(N_NODES + 7) / 8, 256, 0, stream>>>(
        bufB, csr, row, cnt, selfnorm, nullptr, bufA, N_NODES);
    gemm_mfma<HID, HID, true><<<gX * (HID / 64), 256, 0, stream>>>(bufA, Wt1, b1, bufB, N_NODES);

    // ---- layer 3: P = H2 @ W2 (no act), out = A*P + b2 (64-wide gather) ----
    gemm_mfma<HID, NCLS, false><<<gX * (NCLS / 64), 256, 0, stream>>>(bufB, Wt2, nullptr, bufA, N_NODES);
    agg_csr<NCLS, 8, true, true><<<(N_NODES + 31) / 32, 256, 0, stream>>>(
        bufA, csr, row, cnt, selfnorm, b2, outp, N_NODES);
}

// Round 4
// 519.347 us; speedup vs baseline: 1.0698x; 1.0698x over previous
//
#include <hip/hip_runtime.h>

#define N_NODES 100000
#define F_IN 128
#define HID 256
#define NCLS 64
#define N_EDGES 1600000

typedef _Float16 f16;
typedef f16 half8 __attribute__((ext_vector_type(8)));
typedef f16 half4 __attribute__((ext_vector_type(4)));
typedef float f32x4 __attribute__((ext_vector_type(4)));
typedef unsigned long long u64;

#define FIXED_SCALE 67108864.0f   // 2^26

// ---------------------------------------------------------------------------
// degp[i]: packed u64 = (edge_count << 40) | fixed_point_26(weighted_deg)
// Init = fixed-point 1.0 (the self-loop weight), count 0.
// ---------------------------------------------------------------------------
__global__ void k_init(unsigned long long* __restrict__ degp, int n) {
    int i = blockIdx.x * 256 + threadIdx.x;
    if (i < n) degp[i] = (unsigned long long)(1u << 26);
}

// Mega kernel: k_deg atomics (blocks [0,EB)) run with idle VALU/HBM pipes;
// fp16 conversions ride along in trailing blocks, hidden under the atomic
// latency envelope. All parts are mutually independent.
#define EB   6250    // N_EDGES/256
#define XB   12500   // N_NODES*F_IN/4/256
#define W0B  128     // F_IN*HID/256
#define W1B  256     // HID*HID/256
#define W2B  64      // HID*NCLS/256
__global__ __launch_bounds__(256) void mega1(
        const int* __restrict__ dst, const float* __restrict__ ew,
        unsigned long long* __restrict__ degp, int* __restrict__ seq,
        const float* __restrict__ x, f16* __restrict__ xh,
        const float* __restrict__ W0, f16* __restrict__ Wt0,
        const float* __restrict__ W1, f16* __restrict__ Wt1,
        const float* __restrict__ W2, f16* __restrict__ Wt2) {
    int bid = blockIdx.x;
    int t = threadIdx.x;
    if (bid < EB) {
        int i = bid * 256 + t;
        if (i < N_EDGES) {
            unsigned long long c = (1ULL << 40) |
                (unsigned long long)__float2uint_rn(ew[i] * FIXED_SCALE);
            unsigned long long old = atomicAdd(&degp[dst[i]], c);
            seq[i] = (int)(old >> 40);       // this edge's slot within its dst segment
        }
    } else if (bid < EB + XB) {
        int i = (bid - EB) * 256 + t;        // float4 index over x
        if (i < N_NODES * (F_IN / 4)) {
            float4 v = *(const float4*)&x[(size_t)i * 4];
            half4 o;
            o[0] = (f16)v.x; o[1] = (f16)v.y; o[2] = (f16)v.z; o[3] = (f16)v.w;
            *(half4*)&xh[(size_t)i * 4] = o;
        }
    } else if (bid < EB + XB + W0B) {
        int i = (bid - EB - XB) * 256 + t;   // W0[F_IN][HID] -> Wt0[HID][F_IN]
        int k = i / HID, d = i % HID;
        Wt0[d * F_IN + k] = (f16)W0[i];
    } else if (bid < EB + XB + W0B + W1B) {
        int i = (bid - EB - XB - W0B) * 256 + t;
        int k = i / HID, d = i % HID;
        Wt1[d * HID + k] = (f16)W1[i];
    } else {
        int i = (bid - EB - XB - W0B - W1B) * 256 + t;
        int k = i / NCLS, d = i % NCLS;
        Wt2[d * HID + k] = (f16)W2[i];
    }
}

// k_dis folded into scan1: compute cnt/dis/selfnorm from degp inline, then scan.
__global__ void k_scan1(const unsigned long long* __restrict__ degp,
                        int* __restrict__ cnt, float* __restrict__ dis,
                        float* __restrict__ selfnorm,
                        int* __restrict__ incl, int* __restrict__ bsum, int n) {
    __shared__ int s[256];
    int t = threadIdx.x;
    int i = blockIdx.x * 256 + t;
    int v = 0;
    if (i < n) {
        unsigned long long p = degp[i];
        v = (int)(p >> 40);
        cnt[i] = v;
        float deg = (float)(p & ((1ULL << 40) - 1)) * (1.0f / FIXED_SCALE);
        float d = rsqrtf(deg);
        dis[i] = d;
        selfnorm[i] = d * d;
    }
    s[t] = v;
    __syncthreads();
    #pragma unroll
    for (int off = 1; off < 256; off <<= 1) {
        int x = (t >= off) ? s[t - off] : 0;
        __syncthreads();
        s[t] += x;
        __syncthreads();
    }
    if (i < n) incl[i] = s[t];
    if (t == 255) bsum[blockIdx.x] = s[255];
}

__global__ void k_scan2(const int* __restrict__ bsum, int* __restrict__ boff, int nb) {
    __shared__ int s[512];
    int t = threadIdx.x;
    int v = (t < nb) ? bsum[t] : 0;
    s[t] = v;
    __syncthreads();
    #pragma unroll
    for (int off = 1; off < 512; off <<= 1) {
        int x = (t >= off) ? s[t - off] : 0;
        __syncthreads();
        s[t] += x;
        __syncthreads();
    }
    if (t < nb) boff[t] = s[t] - v;
}

// row[i] = global exclusive start (in-place over incl); row is NOT mutated later
__global__ void k_scan3(int* __restrict__ row, const int* __restrict__ cnt,
                        const int* __restrict__ boff, int n) {
    int i = blockIdx.x * 256 + threadIdx.x;
    if (i < n) row[i] = row[i] - cnt[i] + boff[i >> 8];
}

// atomic-free placement: pos = row_start[dst] + seq (from mega1's atomic return)
__global__ void k_place(const int* __restrict__ src, const int* __restrict__ dst,
                        const float* __restrict__ w, const int* __restrict__ seq,
                        const int* __restrict__ row, const float* __restrict__ dis,
                        int2* __restrict__ csr, int e) {
    int i = blockIdx.x * 256 + threadIdx.x;
    if (i < e) {
        int s = src[i], d = dst[i];
        float nw = dis[s] * w[i] * dis[d];
        int pos = row[d] + seq[i];
        csr[pos] = make_int2(s, __float_as_int(nw));
    }
}

// ---------------------------------------------------------------------------
// MFMA GEMM: out[n, c] = sum_k in[n, k] * W[k, c]  (+bias, relu if BIAS_RELU)
// Block tile 128x64, 4 waves, each wave 32 rows x 64 cols = 2x4 mfma 16x16x32.
// VGPR-staging body (verified); 1D grid + bijective XCD-chunk swizzle so
// the NB column-blocks sharing an A-panel land on the same XCD's L2.
// NOTE: global_load_lds staging variant killed the container twice -- do not
// reintroduce without isolated re-testing.
// ---------------------------------------------------------------------------
template <int K, int DOUT, bool BIAS_RELU>
__global__ __launch_bounds__(256) void gemm_mfma(const f16* __restrict__ in,
                                                 const f16* __restrict__ Wt,  // [DOUT][K]
                                                 const float* __restrict__ bias,
                                                 f16* __restrict__ out,
                                                 int nNodes) {
    constexpr int BM = 128, BN = 64, BK = 32;
    constexpr int NB = DOUT / BN;
    constexpr int AP = 40;
    constexpr int CP = 72;
    constexpr int SMEM = (BM * AP + BN * AP) > (BM * CP) ? (BM * AP + BN * AP) : (BM * CP);
    __shared__ f16 smem[SMEM];
    f16* As = smem;
    f16* Bs = smem + BM * AP;

    // bijective XCD-chunked swizzle (m204): dispatched block b (XCD ~ b%8)
    // processes work index wk so each XCD gets a contiguous chunk.
    const int nwg = gridDim.x;
    const int b = blockIdx.x;
    const int q = nwg >> 3, r = nwg & 7, xcd = b & 7;
    const int wk = (xcd < r ? xcd * (q + 1) : r * (q + 1) + (xcd - r) * q) + (b >> 3);
    const int bx = wk / NB, by = wk % NB;

    const int t = threadIdx.x;
    const int w = t >> 6;
    const int lane = t & 63;
    const int quad = lane >> 4;
    const int l16 = lane & 15;
    const int nodeBase = bx * BM;
    const int colBase = by * BN;

    f32x4 acc[2][4] = {};

    for (int k0 = 0; k0 < K; k0 += BK) {
        {
            int koff = (t & 3) * 8;
            #pragma unroll
            for (int p = 0; p < 2; ++p) {
                int r2 = (t >> 2) + p * 64;
                int gn = nodeBase + r2;
                if (gn >= nNodes) gn = nNodes - 1;
                half8 v = *(const half8*)&in[(size_t)gn * K + k0 + koff];
                *(half8*)&As[r2 * AP + koff] = v;
            }
        }
        {
            int koff = (t & 3) * 8;
            int c = t >> 2;
            half8 v = *(const half8*)&Wt[(size_t)(colBase + c) * K + k0 + koff];
            *(half8*)&Bs[c * AP + koff] = v;
        }
        __syncthreads();

        half8 a[2];
        #pragma unroll
        for (int rt = 0; rt < 2; ++rt)
            a[rt] = *(const half8*)&As[(w * 32 + rt * 16 + l16) * AP + quad * 8];
        #pragma unroll
        for (int ct = 0; ct < 4; ++ct) {
            half8 bf = *(const half8*)&Bs[(ct * 16 + l16) * AP + quad * 8];
            acc[0][ct] = __builtin_amdgcn_mfma_f32_16x16x32_f16(a[0], bf, acc[0][ct], 0, 0, 0);
            acc[1][ct] = __builtin_amdgcn_mfma_f32_16x16x32_f16(a[1], bf, acc[1][ct], 0, 0, 0);
        }
        __syncthreads();
    }

    float bv[4];
    #pragma unroll
    for (int ct = 0; ct < 4; ++ct)
        bv[ct] = BIAS_RELU ? bias[colBase + ct * 16 + l16] : 0.0f;

    f16* Cs = smem;
    #pragma unroll
    for (int rt = 0; rt < 2; ++rt)
        #pragma unroll
        for (int ct = 0; ct < 4; ++ct)
            #pragma unroll
            for (int rr2 = 0; rr2 < 4; ++rr2) {
                int rr = w * 32 + rt * 16 + quad * 4 + rr2;
                int cc = ct * 16 + l16;
                float v = acc[rt][ct][rr2];
                if (BIAS_RELU) v = fmaxf(v + bv[ct], 0.0f);
                Cs[rr * CP + cc] = (f16)v;
            }
    __syncthreads();
    #pragma unroll
    for (int p = 0; p < 4; ++p) {
        int rr = (t >> 3) + p * 32;
        int gn = nodeBase + rr;
        int chunk = (t & 7) * 8;
        if (gn < nNodes)
            *(half8*)&out[(size_t)gn * DOUT + colBase + chunk] =
                *(const half8*)&Cs[rr * CP + chunk];
    }
}

// ---------------------------------------------------------------------------
// CSR aggregation (fp16 h): out[d,:] = sn[d]*h[d,:] (+bias) + sum_e w_e*h[src_e,:]
// TPN lanes per node, 8 cols per lane (half8 = 16B), fp32 accumulate.
// Unroll-4 with PLAIN cached loads (R3 post-mortem: nontemporal csr loads
// dropped shared csr lines from L2 -> +18MB FETCH, -10%; nt removed).
// ---------------------------------------------------------------------------
template <int DOUT, int TPN, bool HAS_BIAS, bool OUT_F32>
__global__ __launch_bounds__(256) void agg_csr(const f16* __restrict__ h,
                                               const int2* __restrict__ csr,
                                               const int* __restrict__ row,
                                               const int* __restrict__ cnt,
                                               const float* __restrict__ sn,
                                               const float* __restrict__ bias,
                                               void* __restrict__ outv, int nNodes) {
    constexpr int NPB = 256 / TPN;
    int node = blockIdx.x * NPB + threadIdx.x / TPN;
    if (node >= nNodes) return;
    int lane = threadIdx.x % TPN;
    int col = lane * 8;

    float s = sn[node];
    half8 hv = *(const half8*)&h[(size_t)node * DOUT + col];
    float acc[8];
    #pragma unroll
    for (int i = 0; i < 8; ++i)
        acc[i] = s * (float)hv[i] + (HAS_BIAS ? bias[col + i] : 0.0f);

    int e = row[node];
    int end = e + cnt[node];

    for (; e + 3 < end; e += 4) {
        int2 e0 = csr[e], e1 = csr[e + 1], e2 = csr[e + 2], e3 = csr[e + 3];
        float w0 = __int_as_float(e0.y), w1 = __int_as_float(e1.y);
        float w2 = __int_as_float(e2.y), w3 = __int_as_float(e3.y);
        half8 a0 = *(const half8*)&h[(size_t)e0.x * DOUT + col];
        half8 a1 = *(const half8*)&h[(size_t)e1.x * DOUT + col];
        half8 a2 = *(const half8*)&h[(size_t)e2.x * DOUT + col];
        half8 a3 = *(const half8*)&h[(size_t)e3.x * DOUT + col];
        #pragma unroll
        for (int i = 0; i < 8; ++i)
            acc[i] += w0 * (float)a0[i] + w1 * (float)a1[i]
                    + w2 * (float)a2[i] + w3 * (float)a3[i];
    }
    for (; e + 1 < end; e += 2) {
        int2 e0 = csr[e], e1 = csr[e + 1];
        float w0 = __int_as_float(e0.y), w1 = __int_as_float(e1.y);
        half8 a0 = *(const half8*)&h[(size_t)e0.x * DOUT + col];
        half8 a1 = *(const half8*)&h[(size_t)e1.x * DOUT + col];
        #pragma unroll
        for (int i = 0; i < 8; ++i) acc[i] += w0 * (float)a0[i] + w1 * (float)a1[i];
    }
    if (e < end) {
        int2 e0 = csr[e];
        float w0 = __int_as_float(e0.y);
        half8 a0 = *(const half8*)&h[(size_t)e0.x * DOUT + col];
        #pragma unroll
        for (int i = 0; i < 8; ++i) acc[i] += w0 * (float)a0[i];
    }

    if (OUT_F32) {
        float* out = (float*)outv;
        float4 r0 = make_float4(acc[0], acc[1], acc[2], acc[3]);
        float4 r1 = make_float4(acc[4], acc[5], acc[6], acc[7]);
        *(float4*)&out[(size_t)node * DOUT + col] = r0;
        *(float4*)&out[(size_t)node * DOUT + col + 4] = r1;
    } else {
        f16* out = (f16*)outv;
        half8 o;
        #pragma unroll
        for (int i = 0; i < 8; ++i) o[i] = (f16)acc[i];
        *(half8*)&out[(size_t)node * DOUT + col] = o;
    }
}

// ---------------------------------------------------------------------------
extern "C" void kernel_launch(void* const* d_in, const int* in_sizes, int n_in,
                              void* d_out, int out_size, void* d_ws, size_t ws_size,
                              hipStream_t stream) {
    const float* x  = (const float*)d_in[0];
    const int*   ei = (const int*)d_in[1];
    const float* ew = (const float*)d_in[2];
    const float* W0 = (const float*)d_in[3];
    const float* b0 = (const float*)d_in[4];
    const float* W1 = (const float*)d_in[5];
    const float* b1 = (const float*)d_in[6];
    const float* W2 = (const float*)d_in[7];
    const float* b2 = (const float*)d_in[8];
    const int* src = ei;
    const int* dst = ei + N_EDGES;
    float* outp = (float*)d_out;

    // workspace carve-up (8B-aligned first)
    char* ws = (char*)d_ws;
    unsigned long long* degp = (unsigned long long*)ws;  ws += N_NODES * 8;
    int2*  csr      = (int2*)ws;   ws += (size_t)N_EDGES * 8;
    int*   seq      = (int*)ws;    ws += (size_t)N_EDGES * 4;
    float* dis      = (float*)ws;  ws += N_NODES * 4;
    float* selfnorm = (float*)ws;  ws += N_NODES * 4;
    int*   cnt      = (int*)ws;    ws += N_NODES * 4;
    int*   row      = (int*)ws;    ws += N_NODES * 4;
    int*   bsum     = (int*)ws;    ws += 512 * 4;
    int*   boff     = (int*)ws;    ws += 512 * 4;
    f16*   xh       = (f16*)ws;    ws += (size_t)N_NODES * F_IN * 2;
    f16*   Wt0      = (f16*)ws;    ws += F_IN * HID * 2;
    f16*   Wt1      = (f16*)ws;    ws += HID * HID * 2;
    f16*   Wt2      = (f16*)ws;    ws += HID * NCLS * 2;
    f16*   bufA     = (f16*)ws;    ws += (size_t)N_NODES * HID * 2;
    f16*   bufB     = (f16*)ws;    ws += (size_t)N_NODES * HID * 2;

    const int nb = (N_NODES + 255) / 256;   // 391
    const int eb = (N_EDGES + 255) / 256;   // 6250

    // ---- CSR build + norm (conversions hidden under the atomic pass) ----
    k_init<<<nb, 256, 0, stream>>>(degp, N_NODES);
    mega1<<<EB + XB + W0B + W1B + W2B, 256, 0, stream>>>(
        dst, ew, degp, seq, x, xh, W0, Wt0, W1, Wt1, W2, Wt2);
    k_scan1<<<nb, 256, 0, stream>>>(degp, cnt, dis, selfnorm, row, bsum, N_NODES);
    k_scan2<<<1, 512, 0, stream>>>(bsum, boff, nb);
    k_scan3<<<nb, 256, 0, stream>>>(row, cnt, boff, N_NODES);
    k_place<<<eb, 256, 0, stream>>>(src, dst, ew, seq, row, dis, csr, N_EDGES);

    const int gX = (N_NODES + 127) / 128;   // 782

    // ---- layer 1: g1 = A*X (128-wide gather), H1 = relu(g1 @ W0 + b0) ----
    agg_csr<F_IN, 16, false, false><<<(N_NODES + 15) / 16, 256, 0, stream>>>(
        xh, csr, row, cnt, selfnorm, nullptr, bufA, N_NODES);
    gemm_mfma<F_IN, HID, true><<<gX * (HID / 64), 256, 0, stream>>>(bufA, Wt0, b0, bufB, N_NODES);

    // ---- layer 2: g2 = A*H1 (256-wide gather), H2 = relu(g2 @ W1 + b1) ----
    agg_csr<HID, 32, false, false><<<(N_NODES + 7) / 8, 256, 0, stream>>>(
        bufB, csr, row, cnt, selfnorm, nullptr, bufA, N_NODES);
    gemm_mfma<HID, HID, true><<<gX * (HID / 64), 256, 0, stream>>>(bufA, Wt1, b1, bufB, N_NODES);

    // ---- layer 3: P = H2 @ W2 (no act), out = A*P + b2 (64-wide gather) ----
    gemm_mfma<HID, NCLS, false><<<gX * (NCLS / 64), 256, 0, stream>>>(bufB, Wt2, nullptr, bufA, N_NODES);
    agg_csr<NCLS, 8, true, true><<<(N_NODES + 31) / 32, 256, 0, stream>>>(
        bufA, csr, row, cnt, selfnorm, b2, outp, N_NODES);
}